// Round 10
// baseline (447.970 us; speedup 1.0000x reference)
//
#include <hip/hip_runtime.h>

#define NTOP 256

typedef __attribute__((ext_vector_type(8))) short bf16x8;
typedef __attribute__((ext_vector_type(4))) float f32x4;

// round-to-nearest-even split of fp32 into bf16 hi/lo, packed (hi<<16)|lo
__device__ inline unsigned int packbf(float x) {
  unsigned int u = __float_as_uint(x);
  unsigned int r = (u + 0x7fffu + ((u >> 16) & 1u)) & 0xffff0000u;
  float res = x - __uint_as_float(r);
  unsigned int u2 = __float_as_uint(res);
  unsigned int r2 = u2 + 0x7fffu + ((u2 >> 16) & 1u);
  return r | (r2 >> 16);
}

__device__ inline float tanh_fast(float x) {
  float e = __expf(2.f * x);
  return 1.f - 2.f / (e + 1.f);
}

template <int CTRL>
__device__ inline float dpp_f(float v) {
  return __int_as_float(__builtin_amdgcn_update_dpp(
      0, __float_as_int(v), CTRL, 0xf, 0xf, true));
}

// reduce v across each 16-lane row; lane 15 of the row holds the total
__device__ inline float red16(float v) {
  v += dpp_f<0xB1>(v);   // quad_perm xor1
  v += dpp_f<0x4E>(v);   // quad_perm xor2
  v += dpp_f<0x114>(v);  // row_shr:4
  v += dpp_f<0x118>(v);  // row_shr:8
  return v;
}

// ---------------------------------------------------------------- K1
// J=4 outputs x S=16 k per thread (1024 thr): per-lane h slice = 16
// floats -> 4 ds_read_b128/wave -> 64 LDS wave-insts/step (was 256).
// h stored swizzled pos(k)=k+4*(k>>4) (stride 80 B, 2-way banks = free).
// Reduction over the 16 ks-lanes in pure DPP; lane 15 writes 4 outputs.
__global__ __launch_bounds__(1024)
__attribute__((amdgpu_waves_per_eu(4, 4)))
void rsbc_recur(
    const float* __restrict__ Wih, const float* __restrict__ Whh,
    const float* __restrict__ bih, const float* __restrict__ bhh,
    const float* __restrict__ h0, unsigned int* __restrict__ Hpack) {
  __shared__ float hA[320], hB[320];    // swizzled: 16 groups x 20 floats
  const int tid = threadIdx.x;
  const int jg = tid >> 4;              // 0..63: group of 4 outputs
  const int ks = tid & 15;              // k-slice [16ks, 16ks+16)
  const int kb = ks * 20;               // swizzled float offset of slice
  const int j0 = jg * 4;
  const float b0 = bih[j0] + bhh[j0], b1 = bih[j0 + 1] + bhh[j0 + 1];
  const float b2 = bih[j0 + 2] + bhh[j0 + 2], b3 = bih[j0 + 3] + bhh[j0 + 3];
  const int swz = 4 * (j0 >> 4);        // output-group swizzle offset

  // w[jj][kq] = W[j0+jj][16ks+4kq .. +4]   (W_ih; Wc after step 0)
  float4 w[4][4];
#pragma unroll
  for (int jj = 0; jj < 4; ++jj)
#pragma unroll
    for (int kq = 0; kq < 4; ++kq)
      w[jj][kq] = *reinterpret_cast<const float4*>(
          Wih + (j0 + jj) * NTOP + 16 * ks + 4 * kq);

  if (tid < NTOP) hA[tid + 4 * (tid >> 4)] = h0[tid];
  __syncthreads();

  // step 0: h1 = tanh(h0 @ Wih^T + b)
  {
    const float* hq = hA + kb;
    float4 hv0 = *reinterpret_cast<const float4*>(hq);
    float4 hv1 = *reinterpret_cast<const float4*>(hq + 4);
    float4 hv2 = *reinterpret_cast<const float4*>(hq + 8);
    float4 hv3 = *reinterpret_cast<const float4*>(hq + 12);
    float a0 = 0.f, a1 = 0.f, a2 = 0.f, a3 = 0.f;
#define ACC4(aj, jj)                                                        \
  aj = fmaf(hv0.x, w[jj][0].x, aj); aj = fmaf(hv0.y, w[jj][0].y, aj);       \
  aj = fmaf(hv0.z, w[jj][0].z, aj); aj = fmaf(hv0.w, w[jj][0].w, aj);       \
  aj = fmaf(hv1.x, w[jj][1].x, aj); aj = fmaf(hv1.y, w[jj][1].y, aj);       \
  aj = fmaf(hv1.z, w[jj][1].z, aj); aj = fmaf(hv1.w, w[jj][1].w, aj);       \
  aj = fmaf(hv2.x, w[jj][2].x, aj); aj = fmaf(hv2.y, w[jj][2].y, aj);       \
  aj = fmaf(hv2.z, w[jj][2].z, aj); aj = fmaf(hv2.w, w[jj][2].w, aj);       \
  aj = fmaf(hv3.x, w[jj][3].x, aj); aj = fmaf(hv3.y, w[jj][3].y, aj);       \
  aj = fmaf(hv3.z, w[jj][3].z, aj); aj = fmaf(hv3.w, w[jj][3].w, aj);
    ACC4(a0, 0) ACC4(a1, 1) ACC4(a2, 2) ACC4(a3, 3)
    a0 = red16(a0); a1 = red16(a1); a2 = red16(a2); a3 = red16(a3);
    if (ks == 15) {
      float v0 = tanh_fast(a0 + b0), v1 = tanh_fast(a1 + b1);
      float v2 = tanh_fast(a2 + b2), v3 = tanh_fast(a3 + b3);
      hB[j0 + swz + 0] = v0; hB[j0 + swz + 1] = v1;
      hB[j0 + swz + 2] = v2; hB[j0 + swz + 3] = v3;
      Hpack[j0 + 0] = packbf(v0); Hpack[j0 + 1] = packbf(v1);
      Hpack[j0 + 2] = packbf(v2); Hpack[j0 + 3] = packbf(v3);
    }
  }
  // Wc = W_ih + W_hh
#pragma unroll
  for (int jj = 0; jj < 4; ++jj)
#pragma unroll
    for (int kq = 0; kq < 4; ++kq) {
      float4 t = *reinterpret_cast<const float4*>(
          Whh + (j0 + jj) * NTOP + 16 * ks + 4 * kq);
      w[jj][kq].x += t.x; w[jj][kq].y += t.y;
      w[jj][kq].z += t.z; w[jj][kq].w += t.w;
    }
  __syncthreads();

#pragma unroll 1
  for (int s = 1; s < 255; ++s) {
    const float* hq = ((s & 1) ? hB : hA) + kb;
    float* hw = (s & 1) ? hA : hB;
    float4 hv0 = *reinterpret_cast<const float4*>(hq);
    float4 hv1 = *reinterpret_cast<const float4*>(hq + 4);
    float4 hv2 = *reinterpret_cast<const float4*>(hq + 8);
    float4 hv3 = *reinterpret_cast<const float4*>(hq + 12);
    float a0 = 0.f, a1 = 0.f, a2 = 0.f, a3 = 0.f;
    ACC4(a0, 0) ACC4(a1, 1) ACC4(a2, 2) ACC4(a3, 3)
    a0 = red16(a0); a1 = red16(a1); a2 = red16(a2); a3 = red16(a3);
    if (ks == 15) {
      float v0 = tanh_fast(a0 + b0), v1 = tanh_fast(a1 + b1);
      float v2 = tanh_fast(a2 + b2), v3 = tanh_fast(a3 + b3);
      hw[j0 + swz + 0] = v0; hw[j0 + swz + 1] = v1;
      hw[j0 + swz + 2] = v2; hw[j0 + swz + 3] = v3;
      unsigned int* hp = Hpack + s * NTOP + j0;
      hp[0] = packbf(v0); hp[1] = packbf(v1);
      hp[2] = packbf(v2); hp[3] = packbf(v3);
    }
    __syncthreads();
  }
#undef ACC4
}

// ---------------------------------------------------------------- K2
// R2's proven pipeline at BM=64, K-chunk=32: LDS ~70 KB total ->
// 2 blocks/CU, acc[2][4]=32 floats, waves_per_eu(4,4) = 128-reg budget.
// FIX vs R9: segT is its OWN shared array (was aliased past the end of
// smem, stomping logtab while other threads still read it — the race
// that failed correctness).
__global__ __launch_bounds__(512)
__attribute__((amdgpu_waves_per_eu(4, 4)))
void rsbc_gemm_sb(
    const float* __restrict__ z, const unsigned int* __restrict__ Hpack,
    float* __restrict__ out) {
  constexpr int AS = 40;   // ushort stride per staged row (32 + 8 pad)
  constexpr int ES = 260;  // eta row stride (floats)
  __shared__ __align__(16) char smem[66560];   // staging 51.2KB / eta 66.56KB
  __shared__ float logtab[256];
  __shared__ float segT[64 * 8];
  ushort* Ahi = reinterpret_cast<ushort*>(smem);          // 64 rows
  ushort* Alo = Ahi + 64 * AS;
  ushort* Bhi = Alo + 64 * AS;                            // 256 rows
  ushort* Blo = Bhi + 256 * AS;
  float* eta = reinterpret_cast<float*>(smem);            // [64][260]

  const int tid = threadIdx.x;
  const size_t row0 = (size_t)blockIdx.x * 64;
  const int wid = tid >> 6, lane = tid & 63;
  const int wr = wid >> 2, wc = wid & 3;
  const int l15 = lane & 15, l4 = lane >> 4;

  if (tid < 255) logtab[tid] = logf((float)(255 - tid));

  f32x4 acc[2][4];
#pragma unroll
  for (int mt = 0; mt < 2; ++mt)
#pragma unroll
    for (int nt = 0; nt < 4; ++nt) acc[mt][nt] = (f32x4){0.f, 0.f, 0.f, 0.f};

  const int pr = tid >> 3, pq = tid & 7;   // staging: row, float4-idx

  for (int kc = 0; kc < 8; ++kc) {
    const int kb = kc * 32;
    // ---- global loads into regs (issued before barrier)
    float4 zreg = *reinterpret_cast<const float4*>(
        z + (row0 + pr) * NTOP + kb + 4 * pq);
    uint4 hreg[4];
#pragma unroll
    for (int it = 0; it < 4; ++it) {
      int idx = tid + 512 * it;          // 0..2047
      int r = idx >> 3, q = idx & 7;     // r 0..255
      hreg[it] = (r < 255) ? *reinterpret_cast<const uint4*>(
                                 Hpack + r * NTOP + kb + 4 * q)
                           : make_uint4(0u, 0u, 0u, 0u);
    }
    __syncthreads();                     // prev chunk's frag reads done
    // ---- convert + LDS write
    {
      unsigned int p0 = packbf(zreg.x), p1 = packbf(zreg.y),
                   p2 = packbf(zreg.z), p3 = packbf(zreg.w);
      *reinterpret_cast<ushort4*>(&Ahi[pr * AS + 4 * pq]) = make_ushort4(
          (ushort)(p0 >> 16), (ushort)(p1 >> 16),
          (ushort)(p2 >> 16), (ushort)(p3 >> 16));
      *reinterpret_cast<ushort4*>(&Alo[pr * AS + 4 * pq]) = make_ushort4(
          (ushort)(p0 & 0xffff), (ushort)(p1 & 0xffff),
          (ushort)(p2 & 0xffff), (ushort)(p3 & 0xffff));
    }
#pragma unroll
    for (int it = 0; it < 4; ++it) {
      int idx = tid + 512 * it;
      int r = idx >> 3, q = idx & 7;
      uint4 hv = hreg[it];
      *reinterpret_cast<ushort4*>(&Bhi[r * AS + 4 * q]) = make_ushort4(
          (ushort)(hv.x >> 16), (ushort)(hv.y >> 16),
          (ushort)(hv.z >> 16), (ushort)(hv.w >> 16));
      *reinterpret_cast<ushort4*>(&Blo[r * AS + 4 * q]) = make_ushort4(
          (ushort)(hv.x & 0xffff), (ushort)(hv.y & 0xffff),
          (ushort)(hv.z & 0xffff), (ushort)(hv.w & 0xffff));
    }
    __syncthreads();                     // staging visible
    // ---- fragments + 24 MFMA (one K=32 step, bf16x3)
    const int ko = l4 * 8;
    bf16x8 ah[2], al[2];
#pragma unroll
    for (int mt = 0; mt < 2; ++mt) {
      int r = 32 * wr + 16 * mt + l15;
      ah[mt] = *reinterpret_cast<const bf16x8*>(&Ahi[r * AS + ko]);
      al[mt] = *reinterpret_cast<const bf16x8*>(&Alo[r * AS + ko]);
    }
#pragma unroll
    for (int nt = 0; nt < 4; ++nt) {
      int n = 64 * wc + 16 * nt + l15;
      bf16x8 bh = *reinterpret_cast<const bf16x8*>(&Bhi[n * AS + ko]);
      bf16x8 bl = *reinterpret_cast<const bf16x8*>(&Blo[n * AS + ko]);
#pragma unroll
      for (int mt = 0; mt < 2; ++mt) {
        acc[mt][nt] = __builtin_amdgcn_mfma_f32_16x16x32_bf16(
            ah[mt], bh, acc[mt][nt], 0, 0, 0);
        acc[mt][nt] = __builtin_amdgcn_mfma_f32_16x16x32_bf16(
            ah[mt], bl, acc[mt][nt], 0, 0, 0);
        acc[mt][nt] = __builtin_amdgcn_mfma_f32_16x16x32_bf16(
            al[mt], bh, acc[mt][nt], 0, 0, 0);
      }
    }
  }
  __syncthreads();                       // frag reads done; smem -> eta

  // ---- eta = sigmoid(logits) -> LDS
  // C/D layout: row = 32wr+16mt+4*l4+i, col = 64wc+16nt+l15
#pragma unroll
  for (int mt = 0; mt < 2; ++mt) {
    int rbase = 32 * wr + 16 * mt + 4 * l4;
#pragma unroll
    for (int nt = 0; nt < 4; ++nt) {
      int c = 64 * wc + 16 * nt + l15;
#pragma unroll
      for (int i = 0; i < 4; ++i) {
        float x = acc[mt][nt][i];
        eta[(rbase + i) * ES + c] = 1.f / (1.f + __expf(-x));
      }
    }
  }
  __syncthreads();

  // ---- stick-breaking: 8 threads per row, segmented cumprod
  const int r = tid >> 3, qk = tid & 7;
  const int kbeg = 32 * qk, kend = (qk == 7) ? 255 : 32 * qk + 32;
  float* er = &eta[r * ES];
  {
    float cp = 1.f;
#pragma unroll 4
    for (int k = kbeg; k < kend; ++k) {
      float x = er[k] - logtab[k];
      float zc = 1.f / (1.f + __expf(-x));
      zc = fminf(fmaxf(zc, 1.1754943508222875e-38f), 0.99999988079071045f);
      er[k] = zc * cp;
      cp *= 1.f - zc;
    }
    segT[r * 8 + qk] = cp;
  }
  __syncthreads();
  {
    float p = 1.f;
#pragma unroll
    for (int i = 0; i < 7; ++i)
      if (i < qk) p *= segT[r * 8 + i];
    if (qk > 0) {
#pragma unroll 4
      for (int k = kbeg; k < kend; ++k) er[k] *= p;
    }
    if (qk == 7) er[255] = p * segT[r * 8 + 7];
  }
  __syncthreads();

  // ---- coalesced store: 64 rows x 64 float4
#pragma unroll
  for (int it = 0; it < 8; ++it) {
    int idx = tid + 512 * it;            // 0..4095
    int rr = idx >> 6, cq = idx & 63;
    float4 vv = *reinterpret_cast<const float4*>(&eta[rr * ES + 4 * cq]);
    *reinterpret_cast<float4*>(&out[(row0 + rr) * NTOP + 4 * cq]) = vv;
  }
}

// ---------------------------------------------------------------- launch
extern "C" void kernel_launch(void* const* d_in, const int* in_sizes, int n_in,
                              void* d_out, int out_size, void* d_ws, size_t ws_size,
                              hipStream_t stream) {
  const float* z   = (const float*)d_in[0];
  const float* h0  = (const float*)d_in[1];
  const float* Wih = (const float*)d_in[2];
  const float* Whh = (const float*)d_in[3];
  const float* bih = (const float*)d_in[4];
  const float* bhh = (const float*)d_in[5];
  float* out = (float*)d_out;
  unsigned int* Hpack = (unsigned int*)d_ws;  // 255*256 uint32

  rsbc_recur<<<1, 1024, 0, stream>>>(Wih, Whh, bih, bhh, h0, Hpack);
  const int nrows = out_size / NTOP;          // 131072
  const int blocks = nrows / 64;              // 2048
  rsbc_gemm_sb<<<blocks, 512, 0, stream>>>(z, Hpack, out);
}